// Round 2
// baseline (99.116 us; speedup 1.0000x reference)
//
#include <hip/hip_runtime.h>
#include <math.h>

// One 256-thread block per walker b. S=2, N=8, D=256, I=4.
// LDS: h only (19.3 KB) -> 8 blocks/CU. W/b/decay/pi read from global (L1/L2-hot).
// Phases: stage h -> dist + k-tiled dot -> env*lin=M -> 16 serial 7x7 dets -> out.

__global__ __launch_bounds__(256, 8)
void orbital_cof_kernel(const float* __restrict__ h_g,   // (B,16,256)
                        const float* __restrict__ r_g,   // (B,16,4,3)
                        const float* __restrict__ W_g,   // (2,256,8)
                        const float* __restrict__ b_g,   // (2,8)
                        const float* __restrict__ dec_g, // (2,4,8)
                        const float* __restrict__ pi_g,  // (2,4,8)
                        float* __restrict__ out,         // (2,B,8,256)
                        int nb)
{
    __shared__ float hs[16][260];        // 16640 B, padded: 2-way max on dot reads
    __shared__ float partial[4][16][8];  // [quarter][sn][k] 2 KB
    __shared__ float Ms[2][8][8];
    __shared__ float anti_s[16];
    __shared__ float dist_s[64];         // [s*32 + n*4 + i]

    const int t = threadIdx.x;
    const int b = blockIdx.x;

    // ---- stage h (1024 float4, coalesced) ----
    const float4* h4 = (const float4*)(h_g + (size_t)b * 4096);
#pragma unroll
    for (int it = 0; it < 4; ++it) {
        int f4 = t + it * 256;          // 0..1023
        int row = f4 >> 6;              // s*8+n
        int d4 = (f4 & 63) << 2;
        float4 v = h4[f4];
        *(float4*)&hs[row][d4] = v;
    }
    __syncthreads();

    // ---- distances (t<64): t = s*32 + n*4 + i matches r flat layout ----
    if (t < 64) {
        const float* rp = r_g + (size_t)b * 192 + t * 3;
        float x = rp[0], y = rp[1], z = rp[2];
        dist_s[t] = sqrtf(x * x + y * y + z * z);
    }

    // ---- k-tiled dot: thread = (quarter=t>>6, sn=(t>>2)&15, kpair=t&3) ----
    {
        int quarter = t >> 6;
        int sn = (t >> 2) & 15;
        int kp = t & 3;
        int s = sn >> 3;
        const float* hrow = &hs[sn][quarter * 64];
        // W_g flat idx = s*2048 + d*8 + k ; d = quarter*64 + dd
        const float* wbase = W_g + s * 2048 + quarter * 512 + kp * 2;
        float acc0 = 0.f, acc1 = 0.f;
#pragma unroll
        for (int dd = 0; dd < 64; dd += 4) {
            float4 hv = *(const float4*)&hrow[dd];
            float2 w0 = *(const float2*)&wbase[(dd + 0) * 8];
            float2 w1 = *(const float2*)&wbase[(dd + 1) * 8];
            float2 w2 = *(const float2*)&wbase[(dd + 2) * 8];
            float2 w3 = *(const float2*)&wbase[(dd + 3) * 8];
            acc0 = fmaf(hv.x, w0.x, acc0); acc1 = fmaf(hv.x, w0.y, acc1);
            acc0 = fmaf(hv.y, w1.x, acc0); acc1 = fmaf(hv.y, w1.y, acc1);
            acc0 = fmaf(hv.z, w2.x, acc0); acc1 = fmaf(hv.z, w2.y, acc1);
            acc0 = fmaf(hv.w, w3.x, acc0); acc1 = fmaf(hv.w, w3.y, acc1);
        }
        partial[quarter][sn][kp * 2]     = acc0;
        partial[quarter][sn][kp * 2 + 1] = acc1;
    }
    __syncthreads();

    // ---- combine + envelope -> orbital matrix M (t<128) ----
    if (t < 128) {
        int s = t >> 6;
        int n = (t >> 3) & 7;
        int k = t & 7;
        int sn = s * 8 + n;
        float lin = partial[0][sn][k] + partial[1][sn][k]
                  + partial[2][sn][k] + partial[3][sn][k] + b_g[s * 8 + k];
        float env = 0.f;
#pragma unroll
        for (int i = 0; i < 4; ++i) {
            float dd = dist_s[s * 32 + n * 4 + i];
            env = fmaf(pi_g[s * 32 + i * 8 + k], __expf(-dd * dec_g[s * 32 + i * 8 + k]), env);
        }
        Ms[s][n][k] = lin * env;
    }
    __syncthreads();

    // ---- 16 cofactor determinants (7x7, partial pivoting, reg-resident) ----
    if (t < 16) {
        int s = t >> 3;
        int n = t & 7;
        float a[7][7];
#pragma unroll
        for (int i = 0; i < 7; ++i) {
            int src = i + (i >= n);     // skip row n
#pragma unroll
            for (int j = 0; j < 7; ++j) a[i][j] = Ms[s][src][j + 1];  // skip col 0
        }
        float det = 1.f;
#pragma unroll
        for (int kk = 0; kk < 7; ++kk) {
#pragma unroll
            for (int i = kk + 1; i < 7; ++i) {
                bool sw = fabsf(a[i][kk]) > fabsf(a[kk][kk]);
#pragma unroll
                for (int j = kk; j < 7; ++j) {
                    float tk = a[kk][j], ti = a[i][j];
                    a[kk][j] = sw ? ti : tk;
                    a[i][j]  = sw ? tk : ti;
                }
                det = sw ? -det : det;
            }
            float piv = a[kk][kk];
            det *= piv;
            float rp = (piv != 0.f) ? (1.f / piv) : 0.f;
#pragma unroll
            for (int i = kk + 1; i < 7; ++i) {
                float f = a[i][kk] * rp;
#pragma unroll
                for (int j = kk + 1; j < 7; ++j) a[i][j] = fmaf(-f, a[kk][j], a[i][j]);
            }
        }
        float sgn = (n & 1) ? -1.f : 1.f;
        anti_s[t] = Ms[s][n][0] * sgn * det;
    }
    __syncthreads();

    // ---- out = h * anti, coalesced float4 stores; tuple layout (s=0, s=1) ----
#pragma unroll
    for (int it = 0; it < 4; ++it) {
        int f4 = t + it * 256;
        int row = f4 >> 6;              // s*8+n
        int d4 = (f4 & 63) << 2;
        float4 v = *(const float4*)&hs[row][d4];
        float aa = anti_s[row];
        float4 o = make_float4(v.x * aa, v.y * aa, v.z * aa, v.w * aa);
        int s = row >> 3;
        int n = row & 7;
        size_t off = (size_t)s * (size_t)nb * 2048 + (size_t)b * 2048 + (size_t)(n * 256 + d4);
        *(float4*)(out + off) = o;
    }
}

extern "C" void kernel_launch(void* const* d_in, const int* in_sizes, int n_in,
                              void* d_out, int out_size, void* d_ws, size_t ws_size,
                              hipStream_t stream) {
    int nb = in_sizes[0] / 4096;        // B = elems / (S*N*D)
    const float* h_g   = (const float*)d_in[0];
    const float* r_g   = (const float*)d_in[1];
    const float* W_g   = (const float*)d_in[2];
    const float* b_g   = (const float*)d_in[3];
    const float* dec_g = (const float*)d_in[4];
    const float* pi_g  = (const float*)d_in[5];
    orbital_cof_kernel<<<dim3(nb), dim3(256), 0, stream>>>(
        h_g, r_g, W_g, b_g, dec_g, pi_g, (float*)d_out, nb);
}

// Round 3
// 56.429 us; speedup vs baseline: 1.7565x; 1.7565x over previous
//
#include <hip/hip_runtime.h>
#include <math.h>

// One 256-thread block per walker. S=2, N=8, D=256, I=4.
// Dot phase: wave=(spin,khalf), lane j owns d in [4j,4j+4); full-width LDS reads
// of h; W held in registers (4x float4 from global, L1-hot); cross-lane
// d-reduction via 32-shuffle halving butterfly. No W LDS tile.

__global__ __launch_bounds__(256, 4)
void orbital_cof_kernel(const float* __restrict__ h_g,   // (B,16,256)
                        const float* __restrict__ r_g,   // (B,16,4,3)
                        const float* __restrict__ W_g,   // (2,256,8)
                        const float* __restrict__ b_g,   // (2,8)
                        const float* __restrict__ dec_g, // (2,4,8)
                        const float* __restrict__ pi_g,  // (2,4,8)
                        float* __restrict__ out,         // (2,B,8,256)
                        int nb)
{
    __shared__ float hs[16][264];    // 16.9 KB, rows 16B-aligned (264*4=1056)
    __shared__ float Ms[2][8][8];
    __shared__ float anti_s[16];
    __shared__ float dist_s[64];     // [s*32 + n*4 + i]

    const int t = threadIdx.x;
    const int b = blockIdx.x;
    const int wave = t >> 6;         // 0..3
    const int lane = t & 63;
    const int s  = wave >> 1;        // spin
    const int kh = wave & 1;         // k half: k = kh*4 + kl

    // ---- W into registers: lane covers d0=4*lane..+4, k=kh*4..+4 ----
    // W_g flat = s*2048 + d*8 + k
    float wv[4][4];                  // [dd][kl], compile-time indexed
    {
        const float* wp = W_g + s * 2048 + lane * 32 + kh * 4;
#pragma unroll
        for (int dd = 0; dd < 4; ++dd) {
            float4 w = *(const float4*)(wp + dd * 8);
            wv[dd][0] = w.x; wv[dd][1] = w.y; wv[dd][2] = w.z; wv[dd][3] = w.w;
        }
    }

    // ---- stage h (coalesced float4; row-contiguous per wave -> conflict-free) ----
    const float4* h4p = (const float4*)(h_g + (size_t)b * 4096);
#pragma unroll
    for (int it = 0; it < 4; ++it) {
        int f4 = t + it * 256;
        int row = f4 >> 6;           // s*8+n
        int d4 = (f4 & 63) << 2;
        float4 v = h4p[f4];
        *(float4*)&hs[row][d4] = v;
    }

    // ---- distances (wave 0): t = s*32 + n*4 + i matches r layout ----
    if (t < 64) {
        const float* rp = r_g + (size_t)b * 192 + t * 3;
        float x = rp[0], y = rp[1], z = rp[2];
        dist_s[t] = sqrtf(x * x + y * y + z * z);
    }
    __syncthreads();

    // ---- dot: p[n*4+kl] = sum over lane's 4 d of h[n][d]*W[d][k] ----
    float v[32];
#pragma unroll
    for (int n = 0; n < 8; ++n) {
        float4 hv = *(const float4*)&hs[s * 8 + n][lane * 4];
#pragma unroll
        for (int kl = 0; kl < 4; ++kl) {
            float acc;
            acc = hv.x * wv[0][kl];
            acc = fmaf(hv.y, wv[1][kl], acc);
            acc = fmaf(hv.z, wv[2][kl], acc);
            acc = fmaf(hv.w, wv[3][kl], acc);
            v[n * 4 + kl] = acc;
        }
    }

    // ---- halving-butterfly reduce over 64 lanes (d-chunks) ----
    // After masks {32,16,8,4,2}: lane j holds orig index (j>>1), summed over
    // the 32 lanes sharing bit0; final xor-1 completes the 64-lane sum.
#pragma unroll
    for (int i = 0; i < 16; ++i) {
        float send = (lane & 32) ? v[i] : v[i + 16];
        float recv = __shfl_xor(send, 32);
        v[i] = ((lane & 32) ? v[i + 16] : v[i]) + recv;
    }
#pragma unroll
    for (int i = 0; i < 8; ++i) {
        float send = (lane & 16) ? v[i] : v[i + 8];
        float recv = __shfl_xor(send, 16);
        v[i] = ((lane & 16) ? v[i + 8] : v[i]) + recv;
    }
#pragma unroll
    for (int i = 0; i < 4; ++i) {
        float send = (lane & 8) ? v[i] : v[i + 4];
        float recv = __shfl_xor(send, 8);
        v[i] = ((lane & 8) ? v[i + 4] : v[i]) + recv;
    }
#pragma unroll
    for (int i = 0; i < 2; ++i) {
        float send = (lane & 4) ? v[i] : v[i + 2];
        float recv = __shfl_xor(send, 4);
        v[i] = ((lane & 4) ? v[i + 2] : v[i]) + recv;
    }
    {
        float send = (lane & 2) ? v[0] : v[1];
        float recv = __shfl_xor(send, 2);
        v[0] = ((lane & 2) ? v[1] : v[0]) + recv;
    }
    float tot = v[0] + __shfl_xor(v[0], 1);

    // ---- env + bias -> Ms (even lanes hold (n,k) = lane>>1) ----
    if ((lane & 1) == 0) {
        int idx = lane >> 1;         // n*4 + kl
        int n = idx >> 2;
        int k = kh * 4 + (idx & 3);
        float lin = tot + b_g[s * 8 + k];
        float env = 0.f;
#pragma unroll
        for (int i = 0; i < 4; ++i) {
            float dd = dist_s[s * 32 + n * 4 + i];
            env = fmaf(pi_g[s * 32 + i * 8 + k], __expf(-dd * dec_g[s * 32 + i * 8 + k]), env);
        }
        Ms[s][n][k] = lin * env;
    }
    __syncthreads();

    // ---- 16 cofactor determinants (7x7, partial pivoting, reg-resident) ----
    if (t < 16) {
        int ss = t >> 3;
        int n = t & 7;
        float a[7][7];
#pragma unroll
        for (int i = 0; i < 7; ++i) {
            int src = i + (i >= n);  // skip row n
#pragma unroll
            for (int j = 0; j < 7; ++j) a[i][j] = Ms[ss][src][j + 1];  // skip col 0
        }
        float det = 1.f;
#pragma unroll
        for (int kk = 0; kk < 7; ++kk) {
#pragma unroll
            for (int i = kk + 1; i < 7; ++i) {
                bool sw = fabsf(a[i][kk]) > fabsf(a[kk][kk]);
#pragma unroll
                for (int j = kk; j < 7; ++j) {
                    float tk = a[kk][j], ti = a[i][j];
                    a[kk][j] = sw ? ti : tk;
                    a[i][j]  = sw ? tk : ti;
                }
                det = sw ? -det : det;
            }
            float piv = a[kk][kk];
            det *= piv;
            float rp = (piv != 0.f) ? (1.f / piv) : 0.f;
#pragma unroll
            for (int i = kk + 1; i < 7; ++i) {
                float f = a[i][kk] * rp;
#pragma unroll
                for (int j = kk + 1; j < 7; ++j) a[i][j] = fmaf(-f, a[kk][j], a[i][j]);
            }
        }
        float sgn = (n & 1) ? -1.f : 1.f;
        anti_s[t] = Ms[ss][n][0] * sgn * det;
    }
    __syncthreads();

    // ---- out = h * anti; coalesced float4 stores; tuple layout (s=0, s=1) ----
#pragma unroll
    for (int it = 0; it < 4; ++it) {
        int f4 = t + it * 256;
        int row = f4 >> 6;           // s*8+n
        int d4 = (f4 & 63) << 2;
        float4 hv = *(const float4*)&hs[row][d4];
        float aa = anti_s[row];
        float4 o = make_float4(hv.x * aa, hv.y * aa, hv.z * aa, hv.w * aa);
        int so = row >> 3;
        int n = row & 7;
        size_t off = (size_t)so * (size_t)nb * 2048 + (size_t)b * 2048 + (size_t)(n * 256 + d4);
        *(float4*)(out + off) = o;
    }
}

extern "C" void kernel_launch(void* const* d_in, const int* in_sizes, int n_in,
                              void* d_out, int out_size, void* d_ws, size_t ws_size,
                              hipStream_t stream) {
    int nb = in_sizes[0] / 4096;     // B = elems / (S*N*D)
    const float* h_g   = (const float*)d_in[0];
    const float* r_g   = (const float*)d_in[1];
    const float* W_g   = (const float*)d_in[2];
    const float* b_g   = (const float*)d_in[3];
    const float* dec_g = (const float*)d_in[4];
    const float* pi_g  = (const float*)d_in[5];
    orbital_cof_kernel<<<dim3(nb), dim3(256), 0, stream>>>(
        h_g, r_g, W_g, b_g, dec_g, pi_g, (float*)d_out, nb);
}